// Round 3
// baseline (219.141 us; speedup 1.0000x reference)
//
#include <hip/hip_runtime.h>

// CTC loss forward. logits (T,N,C) fp32 log-probs, labels (N,S) int32 in
// [1,C), prediction/target sizes (N,).
//
// R10: FUSED single-pass. R9 post-mortem: timed window = workspace poison
// fill(s) (~78us each, fixed harness overhead) + our kernels; the two-phase
// split pays a 67MB comp round-trip (~11us, exactly the R7->R9 kernel-time
// regression) and the standalone alpha wave is latency-bound re-reading its
// compact slice from L3 at ~5GB/s/wave. Fix: one block per batch item n
// (256 blocks x 8 waves); waves 1..7 gather/compact rows into a 2x64-row
// LDS ring (stage 1KB row coalesced float4->regs->LDS, cross-lane ds_read
// gather at labels, exp(+BOOST), 256B compact row); wave 0 runs the serial
// alpha chain straight from LDS (ds_read_b32, ~6cyc). Chunk double-buffer:
// phase c = {gather chunk c+1 || chain chunk c} + one barrier; the 0.4us
// chain hides entirely under the 2.7us/CU gather. Logits are read exactly
// once (134MB); no comp workspace at all.
//
// Alpha tracked in LINEAR space: add/fma/mul chain, cross-lane dep per step
// = one DPP wave_shr1, wave-uniform renorm every 16 steps (DPP-max
// butterfly, logged into logscale). Emissions carry a +BOOST/step boost
// (un-done once at the end); validity masks folded in per step.
//
// Workspace: ws[0..255] = per-item losses only.

constexpr int T = 512, N = 256, C = 256, S = 48;
constexpr int CH  = 64;                // t-rows per chunk
constexpr int NCH = T / CH;            // 8 chunks
constexpr float BOOST = 4.0f;          // per-live-step emission boost (e^4)

__device__ __forceinline__ float wave_shr1(float v, float fill) {
  int r = __builtin_amdgcn_update_dpp(__float_as_int(fill), __float_as_int(v),
                                      0x138, 0xf, 0xf, false);  // wave_shr1
  return __int_as_float(r);
}

#define DPP_MAX(v, ctrl)                                                     \
  fmaxf(v, __int_as_float(__builtin_amdgcn_update_dpp(                       \
               __float_as_int(v), __float_as_int(v), (ctrl), 0xf, 0xf, false)))

// max over 64 lanes, wave-uniform result (alpha >= 0, old-value fallback on
// bcast-inactive lanes is safe).
__device__ __forceinline__ float wavemax(float v) {
  v = DPP_MAX(v, 0x111);               // row_shr:1
  v = DPP_MAX(v, 0x112);               // row_shr:2
  v = DPP_MAX(v, 0x114);               // row_shr:4
  v = DPP_MAX(v, 0x118);               // row_shr:8
  v = DPP_MAX(v, 0x142);               // row_bcast:15
  v = DPP_MAX(v, 0x143);               // row_bcast:31 -> lane 63 = full max
  return __int_as_float(__builtin_amdgcn_readlane(__float_as_int(v), 63));
}

// One 16-step chain group from LDS column PBASE (stride 64 floats/row).
// TG0 = absolute t of d==0; DSTART = 0 normally, 1 for the t=0 slot.
// Renorm (exact bookkeeping) after every group: growth/step <= 3e^4, so
// 16 steps from max~1 stays < 1e36 < fp32 inf.
#define CHAIN_GROUP(PBASE, TG0, DSTART)                                      \
  {                                                                          \
    float e[16];                                                             \
    _Pragma("unroll")                                                        \
    for (int d = (DSTART); d < 16; ++d) e[d] = (PBASE)[(size_t)d * 64];      \
    if ((TG0) + 16 <= Tin) {           /* fast path: all steps live */       \
      _Pragma("unroll")                                                      \
      for (int d = (DSTART); d < 16; ++d) {                                  \
        const float v_ = e[d];                                               \
        const float blank_ = __int_as_float(                                 \
            __builtin_amdgcn_readlane(__float_as_int(v_), 63));              \
        const float eb_ = valid0 ? blank_ : 0.0f;                            \
        const float el_ = valid1 ? v_ : 0.0f;                                \
        const float a1p_ = wave_shr1(a1, 0.0f);                              \
        const float u_ = a1 + a0;          /* off the DPP dependency */      \
        a0 = (a0 + a1p_) * eb_;                                              \
        a1 = fmaf(a1p_, skipf, u_) * el_;                                    \
      }                                                                      \
    } else {                           /* tail: per-step freeze */           \
      _Pragma("unroll")                                                      \
      for (int d = (DSTART); d < 16; ++d) {                                  \
        const float v_ = e[d];                                               \
        const float blank_ = __int_as_float(                                 \
            __builtin_amdgcn_readlane(__float_as_int(v_), 63));              \
        const float eb_ = valid0 ? blank_ : 0.0f;                            \
        const float el_ = valid1 ? v_ : 0.0f;                                \
        const float a1p_ = wave_shr1(a1, 0.0f);                              \
        const float u_ = a1 + a0;                                            \
        const float na0_ = (a0 + a1p_) * eb_;                                \
        const float na1_ = fmaf(a1p_, skipf, u_) * el_;                      \
        if ((TG0) + d < Tin) { a0 = na0_; a1 = na1_; }                       \
      }                                                                      \
    }                                                                        \
    {                                                                        \
      float m_ = fmaxf(wavemax(fmaxf(a0, a1)), 1e-30f);                      \
      const float inv_ = __builtin_amdgcn_rcpf(m_);                          \
      a0 *= inv_; a1 *= inv_;                                                \
      logscale -= __logf(inv_);          /* log exactly what we applied */   \
    }                                                                        \
  }

__launch_bounds__(512, 1)
__global__ void ctc_fused_kernel(const float* __restrict__ lp,
                                 const int*  __restrict__ labels,
                                 const int*  __restrict__ in_len,
                                 const int*  __restrict__ tgt_len,
                                 float* __restrict__ loss_ws) {
  __shared__ float ring[2][CH][64];    // compact rows, double buffer: 32 KB
  __shared__ float stage[7][2][C];     // per-gather-wave row staging: 14 KB

  const int n    = blockIdx.x;
  const int lane = threadIdx.x & 63;
  const int wid  = threadIdx.x >> 6;

  // lab doubles as the gather column: labels for lane<48, blank (0) beyond.
  const int lab      = (lane < S) ? labels[n * S + lane] : 0;
  const int lab_prev = __shfl_up(lab, 1);
  const bool skip   = (lab != 0) && ((lane == 0) || (lab != lab_prev));
  const float skipf = skip ? 1.0f : 0.0f;
  const bool valid0 = (lane <= S);     // pos 2i     in [0, 2S]
  const bool valid1 = (lane <  S);     // pos 2i + 1 in [0, 2S]
  const int Tin = in_len[n];
  const int tl  = tgt_len[n];

  // Gather one 64-row chunk into ring[cc&1]: waves 1..7, rows r == (wid-1)
  // mod 7. All global loads issued up front (<=10 x float4 = 40 VGPR in
  // flight per wave, ~70KB MLP per CU), then staged through LDS for the
  // cross-lane label gather.
  auto gather_chunk = [&](int cc) {
    const int gw = wid - 1;            // 0..6
    float4 v[10];
#pragma unroll
    for (int j = 0; j < 10; ++j) {
      const int r = gw + j * 7;
      if (r < CH)
        v[j] = *reinterpret_cast<const float4*>(
            lp + ((size_t)(cc * CH + r) * N + n) * C + lane * 4);
    }
#pragma unroll
    for (int j = 0; j < 10; ++j) {
      const int r = gw + j * 7;
      if (r < CH) {
        float (&buf)[C] = stage[gw][j & 1];
        *reinterpret_cast<float4*>(&buf[lane * 4]) = v[j];
        const float g = buf[lab];      // same-wave ds_write->ds_read
        ring[cc & 1][r][lane] = __expf(g + BOOST);
      }
    }
  };

  // alpha0 in linear space (no boost at t=0): only lane 0 live.
  const float* nbase = lp + (size_t)n * C;
  float a0 = (lane == 0) ? __expf(nbase[0])   : 0.0f;
  float a1 = (lane == 0) ? __expf(nbase[lab]) : 0.0f;
  float logscale = 0.0f;

  if (wid > 0) gather_chunk(0);        // prologue: chunk 0 resident
  __syncthreads();

#pragma unroll 1
  for (int c = 0; c < NCH; ++c) {
    if (wid > 0) {
      if (c < NCH - 1) gather_chunk(c + 1);
    } else {
      const float* pb = &ring[c & 1][0][lane];
      if (c == 0) {                    // t = 1..63 (t=0 slot skipped)
        CHAIN_GROUP(pb,           0, 1);
        CHAIN_GROUP(pb + 16 * 64, 16, 0);
        CHAIN_GROUP(pb + 32 * 64, 32, 0);
        CHAIN_GROUP(pb + 48 * 64, 48, 0);
      } else {                         // t = 64c .. 64c+63
#pragma unroll
        for (int g = 0; g < 4; ++g)
          CHAIN_GROUP(pb + g * 16 * 64, c * CH + g * 16, 0);
      }
    }
    __syncthreads();
  }

  // tails: alpha[2*tl-1] (lane tl-1, odd slot), alpha[2*tl] (lane tl, even)
  if (wid == 0) {
    const float tail1 = __shfl(a1, tl - 1);
    const float tail2 = __shfl(a0, tl);
    if (lane == 0) {
      const int live = ((Tin < T) ? Tin : T) - 1;  // boosted live steps
      float loss = -(__logf(tail1 + tail2) + logscale - BOOST * (float)live);
      if (!(loss <= 1e29f) || isnan(loss)) loss = 0.0f;  // zero_infinity
      loss_ws[n] = loss / (float)tl;
    }
  }
}

__launch_bounds__(256)
__global__ void ctc_reduce_kernel(const float* __restrict__ loss_ws,
                                  float* __restrict__ out) {
  const int tid = threadIdx.x;
  float v = loss_ws[tid];
#pragma unroll
  for (int off = 32; off > 0; off >>= 1) v += __shfl_down(v, off);
  __shared__ float partial[4];
  if ((tid & 63) == 0) partial[tid >> 6] = v;
  __syncthreads();
  if (tid == 0) {
    float s = (partial[0] + partial[1] + partial[2] + partial[3]) / (float)N;
    if (isnan(s) || isinf(s)) s = 0.0f;            // final sanitize()
    out[0] = s;
  }
}

extern "C" void kernel_launch(void* const* d_in, const int* in_sizes, int n_in,
                              void* d_out, int out_size, void* d_ws, size_t ws_size,
                              hipStream_t stream) {
  const float* lp     = (const float*)d_in[0];     // (T, N, C) fp32
  const int*   labels = (const int*)d_in[1];       // (N, S)
  const int*   plen   = (const int*)d_in[2];       // (N,)
  const int*   tlen   = (const int*)d_in[3];       // (N,)
  float* loss_ws = (float*)d_ws;                   // N floats
  float* out     = (float*)d_out;                  // scalar

  ctc_fused_kernel<<<N, 512, 0, stream>>>(lp, labels, plen, tlen, loss_ws);
  ctc_reduce_kernel<<<1, 256, 0, stream>>>(loss_ws, out);
}

// Round 4
// 193.215 us; speedup vs baseline: 1.1342x; 1.1342x over previous
//
#include <hip/hip_runtime.h>

// CTC loss forward. logits (T,N,C) fp32 log-probs, labels (N,S) int32 in
// [1,C), prediction/target sizes (N,).
//
// R11: fused single-pass, SPILL REPAIR. R10 post-mortem: fused kernel 82us
// with WRITE_SIZE ~130MB -- the gather's `float4 v[10]` array under a
// runtime-wid-dependent `if (r < CH)` guard was demoted to scratch
// (VGPR_Count=44 proves it: 10 live float4 can't fit), so every staged row
// did a global->scratch->global round trip (~143MB/iter of garbage writes)
// and the load pipeline serialized on scratch latency. Fix: ten NAMED
// float4 registers, unconditional clamped loads (rr=min(gw+7j,63); clamped
// rows redundantly rewrite row 63 with identical values -- benign). All
// other structure identical to R10 (verified absmax 0.0): one block per n,
// waves 1..7 gather/compact rows into a 2x64-row LDS ring (coalesced
// float4 -> named regs -> LDS stage, cross-lane ds_read at labels,
// exp(+BOOST), 256B compact row), wave 0 chains from LDS; chunk
// double-buffer with one barrier per 64 steps. Logits read exactly once.
//
// Alpha tracked in LINEAR space: add/fma/mul chain, cross-lane dep per step
// = one DPP wave_shr1, wave-uniform renorm every 16 steps (DPP-max
// butterfly, logged into logscale). Emissions carry a +BOOST/step boost
// (un-done once at the end); validity masks folded in per step.
//
// Workspace: ws[0..255] = per-item losses only.

constexpr int T = 512, N = 256, C = 256, S = 48;
constexpr int CH  = 64;                // t-rows per chunk
constexpr int NCH = T / CH;            // 8 chunks
constexpr float BOOST = 4.0f;          // per-live-step emission boost (e^4)

__device__ __forceinline__ float wave_shr1(float v, float fill) {
  int r = __builtin_amdgcn_update_dpp(__float_as_int(fill), __float_as_int(v),
                                      0x138, 0xf, 0xf, false);  // wave_shr1
  return __int_as_float(r);
}

#define DPP_MAX(v, ctrl)                                                     \
  fmaxf(v, __int_as_float(__builtin_amdgcn_update_dpp(                       \
               __float_as_int(v), __float_as_int(v), (ctrl), 0xf, 0xf, false)))

// max over 64 lanes, wave-uniform result (alpha >= 0, old-value fallback on
// bcast-inactive lanes is safe).
__device__ __forceinline__ float wavemax(float v) {
  v = DPP_MAX(v, 0x111);               // row_shr:1
  v = DPP_MAX(v, 0x112);               // row_shr:2
  v = DPP_MAX(v, 0x114);               // row_shr:4
  v = DPP_MAX(v, 0x118);               // row_shr:8
  v = DPP_MAX(v, 0x142);               // row_bcast:15
  v = DPP_MAX(v, 0x143);               // row_bcast:31 -> lane 63 = full max
  return __int_as_float(__builtin_amdgcn_readlane(__float_as_int(v), 63));
}

// One 16-step chain group from LDS column PBASE (stride 64 floats/row).
// TG0 = absolute t of d==0; DSTART = 0 normally, 1 for the t=0 slot.
// Renorm (exact bookkeeping) after every group: growth/step <= 3e^4, so
// 16 steps from max~1 stays < 1e36 < fp32 inf.
#define CHAIN_GROUP(PBASE, TG0, DSTART)                                      \
  {                                                                          \
    float e[16];                                                             \
    _Pragma("unroll")                                                        \
    for (int d = (DSTART); d < 16; ++d) e[d] = (PBASE)[(size_t)d * 64];      \
    if ((TG0) + 16 <= Tin) {           /* fast path: all steps live */       \
      _Pragma("unroll")                                                      \
      for (int d = (DSTART); d < 16; ++d) {                                  \
        const float v_ = e[d];                                               \
        const float blank_ = __int_as_float(                                 \
            __builtin_amdgcn_readlane(__float_as_int(v_), 63));              \
        const float eb_ = valid0 ? blank_ : 0.0f;                            \
        const float el_ = valid1 ? v_ : 0.0f;                                \
        const float a1p_ = wave_shr1(a1, 0.0f);                              \
        const float u_ = a1 + a0;          /* off the DPP dependency */      \
        a0 = (a0 + a1p_) * eb_;                                              \
        a1 = fmaf(a1p_, skipf, u_) * el_;                                    \
      }                                                                      \
    } else {                           /* tail: per-step freeze */           \
      _Pragma("unroll")                                                      \
      for (int d = (DSTART); d < 16; ++d) {                                  \
        const float v_ = e[d];                                               \
        const float blank_ = __int_as_float(                                 \
            __builtin_amdgcn_readlane(__float_as_int(v_), 63));              \
        const float eb_ = valid0 ? blank_ : 0.0f;                            \
        const float el_ = valid1 ? v_ : 0.0f;                                \
        const float a1p_ = wave_shr1(a1, 0.0f);                              \
        const float u_ = a1 + a0;                                            \
        const float na0_ = (a0 + a1p_) * eb_;                                \
        const float na1_ = fmaf(a1p_, skipf, u_) * el_;                      \
        if ((TG0) + d < Tin) { a0 = na0_; a1 = na1_; }                       \
      }                                                                      \
    }                                                                        \
    {                                                                        \
      float m_ = fmaxf(wavemax(fmaxf(a0, a1)), 1e-30f);                      \
      const float inv_ = __builtin_amdgcn_rcpf(m_);                          \
      a0 *= inv_; a1 *= inv_;                                                \
      logscale -= __logf(inv_);          /* log exactly what we applied */   \
    }                                                                        \
  }

__launch_bounds__(512, 1)
__global__ void ctc_fused_kernel(const float* __restrict__ lp,
                                 const int*  __restrict__ labels,
                                 const int*  __restrict__ in_len,
                                 const int*  __restrict__ tgt_len,
                                 float* __restrict__ loss_ws) {
  __shared__ float ring[2][CH][64];    // compact rows, double buffer: 32 KB
  __shared__ float stage[7][2][C];     // per-gather-wave row staging: 14 KB

  const int n    = blockIdx.x;
  const int lane = threadIdx.x & 63;
  const int wid  = threadIdx.x >> 6;

  // lab doubles as the gather column: labels for lane<48, blank (0) beyond.
  const int lab      = (lane < S) ? labels[n * S + lane] : 0;
  const int lab_prev = __shfl_up(lab, 1);
  const bool skip   = (lab != 0) && ((lane == 0) || (lab != lab_prev));
  const float skipf = skip ? 1.0f : 0.0f;
  const bool valid0 = (lane <= S);     // pos 2i     in [0, 2S]
  const bool valid1 = (lane <  S);     // pos 2i + 1 in [0, 2S]
  const int Tin = in_len[n];
  const int tl  = tgt_len[n];

  // Gather one 64-row chunk into ring[cc&1]: waves 1..7, rows gw + 7j,
  // clamped to 63 (clamped slots re-write row 63 with identical values --
  // benign same-value race, and the dup loads are L2 hits). Ten NAMED
  // float4 registers, all loads issued before any LDS op: nothing can
  // spill, ~40 VGPR of loads in flight per wave.
  auto gather_chunk = [&](int cc) {
    const int gw = wid - 1;            // 0..6
    const float* base = lp + ((size_t)(cc * CH) * N + n) * C + lane * 4;
    const size_t rstride = (size_t)N * C;

#define ROWIDX(J) ((gw + (J) * 7 < CH) ? gw + (J) * 7 : CH - 1)
#define LOADJ(VJ, J)                                                         \
    const float4 VJ = *reinterpret_cast<const float4*>(                      \
        base + (size_t)ROWIDX(J) * rstride);
    LOADJ(v0, 0) LOADJ(v1, 1) LOADJ(v2, 2) LOADJ(v3, 3) LOADJ(v4, 4)
    LOADJ(v5, 5) LOADJ(v6, 6) LOADJ(v7, 7) LOADJ(v8, 8) LOADJ(v9, 9)
#undef LOADJ

#define USEJ(VJ, J)                                                          \
    {                                                                        \
      float (&buf)[C] = stage[gw][(J) & 1];                                  \
      *reinterpret_cast<float4*>(&buf[lane * 4]) = VJ;                       \
      const float g = buf[lab];        /* same-wave ds_write->ds_read */     \
      ring[cc & 1][ROWIDX(J)][lane] = __expf(g + BOOST);                     \
    }
    USEJ(v0, 0) USEJ(v1, 1) USEJ(v2, 2) USEJ(v3, 3) USEJ(v4, 4)
    USEJ(v5, 5) USEJ(v6, 6) USEJ(v7, 7) USEJ(v8, 8) USEJ(v9, 9)
#undef USEJ
#undef ROWIDX
  };

  // alpha0 in linear space (no boost at t=0): only lane 0 live.
  const float* nbase = lp + (size_t)n * C;
  float a0 = (lane == 0) ? __expf(nbase[0])   : 0.0f;
  float a1 = (lane == 0) ? __expf(nbase[lab]) : 0.0f;
  float logscale = 0.0f;

  if (wid > 0) gather_chunk(0);        // prologue: chunk 0 resident
  __syncthreads();

#pragma unroll 1
  for (int c = 0; c < NCH; ++c) {
    if (wid > 0) {
      if (c < NCH - 1) gather_chunk(c + 1);
    } else {
      const float* pb = &ring[c & 1][0][lane];
      if (c == 0) {                    // t = 1..63 (t=0 slot skipped)
        CHAIN_GROUP(pb,           0, 1);
        CHAIN_GROUP(pb + 16 * 64, 16, 0);
        CHAIN_GROUP(pb + 32 * 64, 32, 0);
        CHAIN_GROUP(pb + 48 * 64, 48, 0);
      } else {                         // t = 64c .. 64c+63
#pragma unroll
        for (int g = 0; g < 4; ++g)
          CHAIN_GROUP(pb + g * 16 * 64, c * CH + g * 16, 0);
      }
    }
    __syncthreads();
  }

  // tails: alpha[2*tl-1] (lane tl-1, odd slot), alpha[2*tl] (lane tl, even)
  if (wid == 0) {
    const float tail1 = __shfl(a1, tl - 1);
    const float tail2 = __shfl(a0, tl);
    if (lane == 0) {
      const int live = ((Tin < T) ? Tin : T) - 1;  // boosted live steps
      float loss = -(__logf(tail1 + tail2) + logscale - BOOST * (float)live);
      if (!(loss <= 1e29f) || isnan(loss)) loss = 0.0f;  // zero_infinity
      loss_ws[n] = loss / (float)tl;
    }
  }
}

__launch_bounds__(256)
__global__ void ctc_reduce_kernel(const float* __restrict__ loss_ws,
                                  float* __restrict__ out) {
  const int tid = threadIdx.x;
  float v = loss_ws[tid];
#pragma unroll
  for (int off = 32; off > 0; off >>= 1) v += __shfl_down(v, off);
  __shared__ float partial[4];
  if ((tid & 63) == 0) partial[tid >> 6] = v;
  __syncthreads();
  if (tid == 0) {
    float s = (partial[0] + partial[1] + partial[2] + partial[3]) / (float)N;
    if (isnan(s) || isinf(s)) s = 0.0f;            // final sanitize()
    out[0] = s;
  }
}

extern "C" void kernel_launch(void* const* d_in, const int* in_sizes, int n_in,
                              void* d_out, int out_size, void* d_ws, size_t ws_size,
                              hipStream_t stream) {
  const float* lp     = (const float*)d_in[0];     // (T, N, C) fp32
  const int*   labels = (const int*)d_in[1];       // (N, S)
  const int*   plen   = (const int*)d_in[2];       // (N,)
  const int*   tlen   = (const int*)d_in[3];       // (N,)
  float* loss_ws = (float*)d_ws;                   // N floats
  float* out     = (float*)d_out;                  // scalar

  ctc_fused_kernel<<<N, 512, 0, stream>>>(lp, labels, plen, tlen, loss_ws);
  ctc_reduce_kernel<<<1, 256, 0, stream>>>(loss_ws, out);
}